// Round 8
// baseline (115820.935 us; speedup 1.0000x reference)
//
#include <hip/hip_runtime.h>
#include <math.h>

// NDDE forward-Euler DDE solve, D=768, N=8192 steps.
// x_{j+1} = x_j + dt * tanh(Wx x_j + Wy x_{j-10} + b),  dt = tau/10.
// Output: trajectory [D][N+1] fp32, out[i*(N+1)+k] = x_k[i].
//
// NUMERICS ARE FROZEN (passes at absmax 16.0 / thr 16.4): fp64-exact dots
// rounded per-dot to fp32; fp32 adds for z; correctly-rounded fp32 tanh via
// fp64; fp32 state update mul-then-add; per-lane column ownership, FMA order
// and shuffle tree IDENTICAL to round 5 (the 20.35 ms best). Round 8 changes
// ONLY the execution topology: 8 independent per-XCD replicas of the exact
// r5 algorithm, each syncing through its own XCD-local L2 (sc0 ops) instead
// of the device coherence point. Every replica computes the bit-identical
// trajectory; all write the same out[] values.
//
// Team formation: 1024 WGs launched; each reads HW_REG_XCC_ID, registers in
// roster[xcc] (agent atomicAdd); slots 0..95 = replica ranks (rank == r5's
// blockIdx), slot >= 96 exits immediately (frees the CU slot so queued WGs
// flow to under-full XCDs). No registration barrier needed.
//
// Sync: tagged-data ring per team in the team XCD's L2 via sc0 (SE-scope,
// L1-bypass) loads/stores. Producers ALSO publish to a per-team agent-scope
// mirror ring; consumers fall back to the mirror every 32 failed sweeps, so
// correctness never depends on WG->XCD placement or sc0 semantics. A global
// abort flag bounds every spin (no-hang guarantee).

#define DD 768
#define NSTEPS 8192
#define NWG_LAUNCH 1024
#define TEAM 96
#define NT 256
#define ROWS_PER_WG 8
#define COLS_PER_LANE 24
#define RING 16

#define ROSTER_OFF 0          // 8 u32 (memset to 0 per launch)
#define ABORT_OFF  32         // 1 u32 (memset to 0 per launch)
#define RINGS_OFF  4096       // 16 rings (8 local + 8 mirror) * RING*DD*8B
#define SLOT_QW    (RING * DD)            // 12288 packs per ring

__device__ __forceinline__ unsigned long long ld_tag(const unsigned long long* p) {
    return __hip_atomic_load(p, __ATOMIC_RELAXED, __HIP_MEMORY_SCOPE_AGENT);
}

// 12 XCD-L2-coherent (sc0 = L1-bypass) 8B loads from p[0..11], one waitcnt.
__device__ __forceinline__ void ld12_sc0(const unsigned long long* p,
                                         unsigned long long* x) {
    asm volatile(
        "global_load_dwordx2 %0, %[a], off sc0\n\t"
        "global_load_dwordx2 %1, %[a], off offset:8 sc0\n\t"
        "global_load_dwordx2 %2, %[a], off offset:16 sc0\n\t"
        "global_load_dwordx2 %3, %[a], off offset:24 sc0\n\t"
        "global_load_dwordx2 %4, %[a], off offset:32 sc0\n\t"
        "global_load_dwordx2 %5, %[a], off offset:40 sc0\n\t"
        "global_load_dwordx2 %6, %[a], off offset:48 sc0\n\t"
        "global_load_dwordx2 %7, %[a], off offset:56 sc0\n\t"
        "global_load_dwordx2 %8, %[a], off offset:64 sc0\n\t"
        "global_load_dwordx2 %9, %[a], off offset:72 sc0\n\t"
        "global_load_dwordx2 %10, %[a], off offset:80 sc0\n\t"
        "global_load_dwordx2 %11, %[a], off offset:88 sc0\n\t"
        "s_waitcnt vmcnt(0)"
        : "=&v"(x[0]), "=&v"(x[1]), "=&v"(x[2]), "=&v"(x[3]),
          "=&v"(x[4]), "=&v"(x[5]), "=&v"(x[6]), "=&v"(x[7]),
          "=&v"(x[8]), "=&v"(x[9]), "=&v"(x[10]), "=&v"(x[11])
        : [a] "v"(p)
        : "memory");
}

__device__ __forceinline__ void st_sc0(unsigned long long* p,
                                       unsigned long long v) {
    asm volatile("global_store_dwordx2 %0, %1, off sc0"
                 :: "v"(p), "v"(v) : "memory");
}

__global__ __launch_bounds__(NT, 3)
void ndde_kernel(const float* __restrict__ x0,
                 const float* __restrict__ tau,
                 const float* __restrict__ Wx,
                 const float* __restrict__ Wy,
                 const float* __restrict__ b,
                 float* __restrict__ out,
                 unsigned long long* __restrict__ rings,
                 unsigned int* __restrict__ roster,
                 unsigned int* __restrict__ abortf)
{
    // Transposed f32 LDS history (r5 layout): column i at
    // hist[slot][(i%24)*32 + i/24]. Reads bank-conflict-free (bank = lane).
    __shared__ float hist[RING][DD];     // 48 KB -> 3 WGs/CU
    __shared__ unsigned s_team, s_rank;

    const int tid = threadIdx.x;

    // ---- team registration: first TEAM WGs per XCD become the replica ----
    if (tid == 0) {
        unsigned xcc;
        asm volatile("s_getreg_b32 %0, hwreg(HW_REG_XCC_ID)" : "=s"(xcc));
        xcc &= 7u;
        unsigned slot = __hip_atomic_fetch_add(&roster[xcc], 1u,
                                               __ATOMIC_RELAXED,
                                               __HIP_MEMORY_SCOPE_AGENT);
        s_team = xcc;
        s_rank = slot;
    }
    __syncthreads();
    const unsigned team = s_team;
    const unsigned rank = s_rank;
    if (rank >= TEAM) return;            // extra WG: free the slot

    unsigned long long* lring = rings + (unsigned long long)team * SLOT_QW;
    unsigned long long* mring = rings + (unsigned long long)(8 + team) * SLOT_QW;

    const int g   = (int)rank;           // == r5's blockIdx.x
    const int r   = tid >> 5;            // local row 0..7
    const int c   = tid & 31;            // lane-within-row 0..31
    const int row = g * ROWS_PER_WG + r;
    const int cb  = c * COLS_PER_LANE;

    const float dtf = tau[0] / 10.0f;

    // ---- stage weights as f32 (r5-identical; cvt to f64 at use, exact) ----
    float wxf[COLS_PER_LANE], wyf[COLS_PER_LANE];
    {
        const float* px = Wx + row * DD + cb;
        const float* py = Wy + row * DD + cb;
        #pragma unroll
        for (int i = 0; i < COLS_PER_LANE / 4; ++i) {
            float4 a = *(const float4*)(px + 4 * i);
            wxf[4*i+0] = a.x; wxf[4*i+1] = a.y; wxf[4*i+2] = a.z; wxf[4*i+3] = a.w;
            float4 d2 = *(const float4*)(py + 4 * i);
            wyf[4*i+0] = d2.x; wyf[4*i+1] = d2.y; wyf[4*i+2] = d2.z; wyf[4*i+3] = d2.w;
        }
    }
    #pragma unroll
    for (int i = 0; i < COLS_PER_LANE; ++i) {
        asm volatile("" : "+v"(wxf[i]));
        asm volatile("" : "+v"(wyf[i]));
    }

    const float brow = b[row];
    float xrow = x0[row];                // lane c==0 carries x_j[row]
    if (c == 0) out[row * (NSTEPS + 1) + 0] = xrow;

    for (int j = 0; j < NSTEPS; ++j) {
        // ---- delayed half: y = x_{j-10} from LDS history (r5-identical) ----
        double dy0 = 0.0, dy1 = 0.0;
        if (j <= 10) {
            const float* ys = x0 + cb;
            #pragma unroll
            for (int i = 0; i < COLS_PER_LANE / 4; ++i) {
                float4 v = *(const float4*)(ys + 4 * i);
                dy0 = fma((double)wyf[4*i+0], (double)v.x, dy0);
                dy1 = fma((double)wyf[4*i+1], (double)v.y, dy1);
                dy0 = fma((double)wyf[4*i+2], (double)v.z, dy0);
                dy1 = fma((double)wyf[4*i+3], (double)v.w, dy1);
            }
        } else {
            const float* hs = hist[(j - 10) & (RING - 1)];
            #pragma unroll
            for (int k = 0; k < COLS_PER_LANE; k += 4) {
                float v0 = hs[(k+0)*32 + c];
                float v1 = hs[(k+1)*32 + c];
                float v2 = hs[(k+2)*32 + c];
                float v3 = hs[(k+3)*32 + c];
                dy0 = fma((double)wyf[k+0], (double)v0, dy0);
                dy1 = fma((double)wyf[k+1], (double)v1, dy1);
                dy0 = fma((double)wyf[k+2], (double)v2, dy0);
                dy1 = fma((double)wyf[k+3], (double)v3, dy1);
            }
        }
        double doty = dy0 + dy1;
        #pragma unroll
        for (int off = 1; off < 32; off <<= 1)
            doty += __shfl_xor(doty, off);

        // ---- wave 0: poll own team's ring via XCD-L2 (sc0); mirror
        // fallback every 32 sweeps keeps correctness placement-independent ----
        if (j >= 1) {
            if (tid < 64) {
                const unsigned tgt = (unsigned)j;
                const int soff = (j & (RING - 1)) * DD + tid * 12;
                const unsigned long long* xl = lring + soff;
                const unsigned long long* xm = mring + soff;
                unsigned long long xv[12];
                int tries = 0;
                for (;;) {
                    ld12_sc0(xl, xv);
                    bool ok = true;
                    #pragma unroll
                    for (int m = 0; m < 12; ++m)
                        ok &= ((unsigned)(xv[m] >> 32) == tgt);
                    if (__all(ok)) break;
                    ++tries;
                    if ((tries & 31) == 0) {
                        #pragma unroll
                        for (int m = 0; m < 12; ++m) xv[m] = ld_tag(xm + m);
                        ok = true;
                        #pragma unroll
                        for (int m = 0; m < 12; ++m)
                            ok &= ((unsigned)(xv[m] >> 32) == tgt);
                        if (__all(ok)) break;
                    }
                    if ((tries & 1023) == 0) {       // no-hang safety valve
                        if (tries >= (1 << 21))
                            __hip_atomic_store(abortf, 1u, __ATOMIC_RELAXED,
                                               __HIP_MEMORY_SCOPE_AGENT);
                        if (__hip_atomic_load(abortf, __ATOMIC_RELAXED,
                                              __HIP_MEMORY_SCOPE_AGENT))
                            break;                   // give up; bench will fail visibly
                    }
                }
                float* hsw = hist[j & (RING - 1)];
                #pragma unroll
                for (int m = 0; m < 12; ++m) {
                    int i = tid * 12 + m;
                    hsw[(i % 24) * 32 + (i / 24)] =
                        __uint_as_float((unsigned)xv[m]);
                }
            }
            __syncthreads();
        }

        // ---- live half: Wx · x_j from LDS (r5-identical) ----
        double dx0 = 0.0, dx1 = 0.0;
        if (j == 0) {
            const float* xs = x0 + cb;
            #pragma unroll
            for (int i = 0; i < COLS_PER_LANE / 4; ++i) {
                float4 v = *(const float4*)(xs + 4 * i);
                dx0 = fma((double)wxf[4*i+0], (double)v.x, dx0);
                dx1 = fma((double)wxf[4*i+1], (double)v.y, dx1);
                dx0 = fma((double)wxf[4*i+2], (double)v.z, dx0);
                dx1 = fma((double)wxf[4*i+3], (double)v.w, dx1);
            }
        } else {
            const float* hs = hist[j & (RING - 1)];
            #pragma unroll
            for (int k = 0; k < COLS_PER_LANE; k += 4) {
                float v0 = hs[(k+0)*32 + c];
                float v1 = hs[(k+1)*32 + c];
                float v2 = hs[(k+2)*32 + c];
                float v3 = hs[(k+3)*32 + c];
                dx0 = fma((double)wxf[k+0], (double)v0, dx0);
                dx1 = fma((double)wxf[k+1], (double)v1, dx1);
                dx0 = fma((double)wxf[k+2], (double)v2, dx0);
                dx1 = fma((double)wxf[k+3], (double)v3, dx1);
            }
        }
        double dotx = dx0 + dx1;
        #pragma unroll
        for (int off = 1; off < 32; off <<= 1)
            dotx += __shfl_xor(dotx, off);

        if (c == 0) {
            // z = (dot1_f32 + dot2_f32) + b, all fp32 adds (np's structure)
            float z = __fadd_rn(__fadd_rn((float)dotx, (float)doty), brow);
            float th;
            float az = fabsf(z);
            if (az < 9.3f) th = (float)tanh((double)z);  // correctly-rounded
            else           th = (z > 0.0f) ? 1.0f : -1.0f;
            // x_next = x + dt*F, fp32 mul then fp32 add (no contraction)
            xrow = __fadd_rn(xrow, __fmul_rn(dtf, th));

            // publish: XCD-local (sc0) + agent-scope mirror; tags carry sync
            unsigned long long pack =
                ((unsigned long long)(unsigned)(j + 1) << 32) |
                (unsigned long long)__float_as_uint(xrow);
            const int po = ((j + 1) & (RING - 1)) * DD + row;
            st_sc0(&lring[po], pack);
            __hip_atomic_store(&mring[po], pack, __ATOMIC_RELAXED,
                               __HIP_MEMORY_SCOPE_AGENT);

            // trajectory write — off the critical path (identical values
            // from all 8 replicas: benign redundancy)
            out[row * (NSTEPS + 1) + (j + 1)] = xrow;
        }
    }
}

extern "C" void kernel_launch(void* const* d_in, const int* in_sizes, int n_in,
                              void* d_out, int out_size, void* d_ws, size_t ws_size,
                              hipStream_t stream) {
    (void)in_sizes; (void)n_in; (void)out_size; (void)ws_size;

    const float* x0  = (const float*)d_in[0];
    const float* tau = (const float*)d_in[1];
    const float* Wx  = (const float*)d_in[2];
    const float* Wy  = (const float*)d_in[3];
    const float* b   = (const float*)d_in[4];
    float* out = (float*)d_out;

    unsigned int* roster     = (unsigned int*)((char*)d_ws + ROSTER_OFF);
    unsigned int* abortf     = (unsigned int*)((char*)d_ws + ABORT_OFF);
    unsigned long long* rings =
        (unsigned long long*)((char*)d_ws + RINGS_OFF);

    // zero rosters + abort flag (graph-capture safe). Rings need no init:
    // strict tag==j matching rejects poison, and stale tags from a previous
    // replay carry the identical deterministic values (benign aliasing).
    hipMemsetAsync((char*)d_ws, 0, 64, stream);

    ndde_kernel<<<NWG_LAUNCH, NT, 0, stream>>>(x0, tau, Wx, Wy, b, out,
                                               rings, roster, abortf);
}

// Round 9
// 26835.751 us; speedup vs baseline: 4.3159x; 4.3159x over previous
//
#include <hip/hip_runtime.h>
#include <math.h>

// NDDE forward-Euler DDE solve, D=768, N=8192 steps.
// x_{j+1} = x_j + dt * tanh(Wx x_j + Wy x_{j-10} + b),  dt = tau/10.
// Output: trajectory [D][N+1] fp32, out[i*(N+1)+k] = x_k[i].
//
// NUMERICS ARE FROZEN (passes at absmax 16.0 / thr 16.4): fp64-exact dots
// rounded per-dot to fp32; fp32 adds for z; correctly-rounded fp32 tanh via
// fp64; fp32 state update mul-then-add; per-lane column ownership, FMA order
// and shuffle tree IDENTICAL to round 5 (20.35 ms best). Round 9 = r5
// verbatim + ONE protocol change: detection via per-wave epoch flags
// (1.5 KB sweep) instead of continuous 6 KB data sweeps; data fetched ONCE,
// tag-verified. Rationale: r6/r7/r8 all show step time scales with
// aggregate poll traffic at the coherence point — so cut it ~16x.
//
// Protocol:
//  - publish: lane c==0 stores (value|tag) pack (relaxed agent) to ring;
//    wave does s_waitcnt vmcnt(0); lane 0 of each wave stores
//    flags[4g+w] = j+1 (plain relaxed store — no RMW (r7 lesson),
//    no fence (r3 lesson)). Tags backstop any store->flag reordering.
//  - detect: wave 0 spins on the 384 flags, 6/lane, all >= j.
//  - fetch: 12 packs/lane, verify tag==j, rare retry. Broadcast to LDS.

#define DD 768
#define NSTEPS 8192
#define NWG 96
#define NT 256
#define ROWS_PER_WG 8
#define COLS_PER_LANE 24
#define RING 16
#define NFLAGS (NWG * 4)

#define FLAGS_OFF 0        // NFLAGS u32, memset to 0 per launch
#define RING_OFF  65536    // RING * DD * 8B packs

__device__ __forceinline__ unsigned long long ld_tag(const unsigned long long* p) {
    return __hip_atomic_load(p, __ATOMIC_RELAXED, __HIP_MEMORY_SCOPE_AGENT);
}
__device__ __forceinline__ unsigned ld_flag(const unsigned* p) {
    return __hip_atomic_load(p, __ATOMIC_RELAXED, __HIP_MEMORY_SCOPE_AGENT);
}

__global__ __launch_bounds__(NT, 1)
void ndde_kernel(const float* __restrict__ x0,
                 const float* __restrict__ tau,
                 const float* __restrict__ Wx,
                 const float* __restrict__ Wy,
                 const float* __restrict__ b,
                 float* __restrict__ out,
                 unsigned long long* __restrict__ ring,
                 unsigned int* __restrict__ flags)
{
    // Transposed f32 LDS history (r5): column i at hist[slot][(i%24)*32+i/24].
    // Reads bank-conflict-free (bank = lane); wave-0 writes 2-way (free).
    __shared__ float hist[RING][DD];     // 48 KB

    const int tid = threadIdx.x;
    const int g   = blockIdx.x;
    const int r   = tid >> 5;            // local row 0..7
    const int c   = tid & 31;            // lane-within-row 0..31
    const int row = g * ROWS_PER_WG + r;
    const int cb  = c * COLS_PER_LANE;

    const float dtf = tau[0] / 10.0f;

    // ---- stage weights as f32 (r5-identical; cvt to f64 at use, exact) ----
    float wxf[COLS_PER_LANE], wyf[COLS_PER_LANE];
    {
        const float* px = Wx + row * DD + cb;
        const float* py = Wy + row * DD + cb;
        #pragma unroll
        for (int i = 0; i < COLS_PER_LANE / 4; ++i) {
            float4 a = *(const float4*)(px + 4 * i);
            wxf[4*i+0] = a.x; wxf[4*i+1] = a.y; wxf[4*i+2] = a.z; wxf[4*i+3] = a.w;
            float4 d2 = *(const float4*)(py + 4 * i);
            wyf[4*i+0] = d2.x; wyf[4*i+1] = d2.y; wyf[4*i+2] = d2.z; wyf[4*i+3] = d2.w;
        }
    }
    #pragma unroll
    for (int i = 0; i < COLS_PER_LANE; ++i) {
        asm volatile("" : "+v"(wxf[i]));
        asm volatile("" : "+v"(wyf[i]));
    }

    const float brow = b[row];
    float xrow = x0[row];                // lane c==0 carries x_j[row]
    if (c == 0) out[row * (NSTEPS + 1) + 0] = xrow;

    for (int j = 0; j < NSTEPS; ++j) {
        // ---- delayed half: y = x_{j-10} from LDS history (r5-identical) ----
        double dy0 = 0.0, dy1 = 0.0;
        if (j <= 10) {
            const float* ys = x0 + cb;
            #pragma unroll
            for (int i = 0; i < COLS_PER_LANE / 4; ++i) {
                float4 v = *(const float4*)(ys + 4 * i);
                dy0 = fma((double)wyf[4*i+0], (double)v.x, dy0);
                dy1 = fma((double)wyf[4*i+1], (double)v.y, dy1);
                dy0 = fma((double)wyf[4*i+2], (double)v.z, dy0);
                dy1 = fma((double)wyf[4*i+3], (double)v.w, dy1);
            }
        } else {
            const float* hs = hist[(j - 10) & (RING - 1)];
            #pragma unroll
            for (int k = 0; k < COLS_PER_LANE; k += 4) {
                float v0 = hs[(k+0)*32 + c];
                float v1 = hs[(k+1)*32 + c];
                float v2 = hs[(k+2)*32 + c];
                float v3 = hs[(k+3)*32 + c];
                dy0 = fma((double)wyf[k+0], (double)v0, dy0);
                dy1 = fma((double)wyf[k+1], (double)v1, dy1);
                dy0 = fma((double)wyf[k+2], (double)v2, dy0);
                dy1 = fma((double)wyf[k+3], (double)v3, dy1);
            }
        }
        double doty = dy0 + dy1;
        #pragma unroll
        for (int off = 1; off < 32; off <<= 1)
            doty += __shfl_xor(doty, off);

        // ---- wave 0: flag-detect (1.5 KB sweep), then ONE tag-verified
        // data fetch, broadcast to LDS ----
        if (j >= 1) {
            if (tid < 64) {
                const unsigned tgt = (unsigned)j;
                const unsigned* fp = flags + tid * 6;
                for (;;) {
                    unsigned f0 = ld_flag(fp + 0);
                    unsigned f1 = ld_flag(fp + 1);
                    unsigned f2 = ld_flag(fp + 2);
                    unsigned f3 = ld_flag(fp + 3);
                    unsigned f4 = ld_flag(fp + 4);
                    unsigned f5 = ld_flag(fp + 5);
                    bool ok = (f0 >= tgt) & (f1 >= tgt) & (f2 >= tgt) &
                              (f3 >= tgt) & (f4 >= tgt) & (f5 >= tgt);
                    if (__all(ok)) break;
                }
                // fetch data once; tags absorb store->flag reordering
                const unsigned long long* xs =
                    ring + (j & (RING - 1)) * DD + tid * 12;
                unsigned long long xv[12];
                for (;;) {
                    #pragma unroll
                    for (int m = 0; m < 12; ++m) xv[m] = ld_tag(xs + m);
                    bool ok = true;
                    #pragma unroll
                    for (int m = 0; m < 12; ++m)
                        ok &= ((unsigned)(xv[m] >> 32) == tgt);
                    if (__all(ok)) break;
                }
                float* hsw = hist[j & (RING - 1)];
                #pragma unroll
                for (int m = 0; m < 12; ++m) {
                    int i = tid * 12 + m;
                    hsw[(i % 24) * 32 + (i / 24)] =
                        __uint_as_float((unsigned)xv[m]);
                }
            }
            __syncthreads();
        }

        // ---- live half: Wx · x_j from LDS (r5-identical) ----
        double dx0 = 0.0, dx1 = 0.0;
        if (j == 0) {
            const float* xs = x0 + cb;
            #pragma unroll
            for (int i = 0; i < COLS_PER_LANE / 4; ++i) {
                float4 v = *(const float4*)(xs + 4 * i);
                dx0 = fma((double)wxf[4*i+0], (double)v.x, dx0);
                dx1 = fma((double)wxf[4*i+1], (double)v.y, dx1);
                dx0 = fma((double)wxf[4*i+2], (double)v.z, dx0);
                dx1 = fma((double)wxf[4*i+3], (double)v.w, dx1);
            }
        } else {
            const float* hs = hist[j & (RING - 1)];
            #pragma unroll
            for (int k = 0; k < COLS_PER_LANE; k += 4) {
                float v0 = hs[(k+0)*32 + c];
                float v1 = hs[(k+1)*32 + c];
                float v2 = hs[(k+2)*32 + c];
                float v3 = hs[(k+3)*32 + c];
                dx0 = fma((double)wxf[k+0], (double)v0, dx0);
                dx1 = fma((double)wxf[k+1], (double)v1, dx1);
                dx0 = fma((double)wxf[k+2], (double)v2, dx0);
                dx1 = fma((double)wxf[k+3], (double)v3, dx1);
            }
        }
        double dotx = dx0 + dx1;
        #pragma unroll
        for (int off = 1; off < 32; off <<= 1)
            dotx += __shfl_xor(dotx, off);

        if (c == 0) {
            // z = (dot1_f32 + dot2_f32) + b, all fp32 adds (np's structure)
            float z = __fadd_rn(__fadd_rn((float)dotx, (float)doty), brow);
            float th;
            float az = fabsf(z);
            if (az < 9.3f) th = (float)tanh((double)z);  // correctly-rounded
            else           th = (z > 0.0f) ? 1.0f : -1.0f;
            // x_next = x + dt*F, fp32 mul then fp32 add (no contraction)
            xrow = __fadd_rn(xrow, __fmul_rn(dtf, th));

            // publish: (value|tag) in one relaxed agent-scope 8B store
            unsigned long long pack =
                ((unsigned long long)(unsigned)(j + 1) << 32) |
                (unsigned long long)__float_as_uint(xrow);
            __hip_atomic_store(&ring[((j + 1) & (RING - 1)) * DD + row], pack,
                               __ATOMIC_RELAXED, __HIP_MEMORY_SCOPE_AGENT);
        }
        // drain this wave's 2 pack stores, then raise the per-wave epoch
        // flag (plain store, no RMW, no fence)
        asm volatile("s_waitcnt vmcnt(0)" ::: "memory");
        if ((tid & 63) == 0) {
            __hip_atomic_store(&flags[g * 4 + (tid >> 6)], (unsigned)(j + 1),
                               __ATOMIC_RELAXED, __HIP_MEMORY_SCOPE_AGENT);
        }
        // trajectory write — off the critical path
        if (c == 0) {
            out[row * (NSTEPS + 1) + (j + 1)] = xrow;
        }
    }
}

extern "C" void kernel_launch(void* const* d_in, const int* in_sizes, int n_in,
                              void* d_out, int out_size, void* d_ws, size_t ws_size,
                              hipStream_t stream) {
    (void)in_sizes; (void)n_in; (void)out_size; (void)ws_size;

    const float* x0  = (const float*)d_in[0];
    const float* tau = (const float*)d_in[1];
    const float* Wx  = (const float*)d_in[2];
    const float* Wy  = (const float*)d_in[3];
    const float* b   = (const float*)d_in[4];
    float* out = (float*)d_out;

    unsigned int* flags      = (unsigned int*)((char*)d_ws + FLAGS_OFF);
    unsigned long long* ring = (unsigned long long*)((char*)d_ws + RING_OFF);

    // zero the per-wave epoch flags (graph-capture safe). Ring needs no
    // init: strict tag==j matching rejects poison and stale replay data.
    hipMemsetAsync(flags, 0, NFLAGS * sizeof(unsigned int), stream);

    ndde_kernel<<<NWG, NT, 0, stream>>>(x0, tau, Wx, Wy, b, out, ring, flags);
}